// Round 5
// baseline (450.980 us; speedup 1.0000x reference)
//
#include <hip/hip_runtime.h>

#define DSZ 128
#define TX 16
#define TY 16
#define PY 24            // TY + 8 halo
#define NVOX 4194304.0f

__global__ void ncc_zero(float* out) { out[0] = 0.0f; }

__device__ __forceinline__ float4 f4add(const float4 a, const float4 b) {
    return make_float4(a.x + b.x, a.y + b.y, a.z + b.z, a.w + b.w);
}
__device__ __forceinline__ float4 f4sub(const float4 a, const float4 b) {
    return make_float4(a.x - b.x, a.y - b.y, a.z - b.z, a.w - b.w);
}

__global__ __launch_bounds__(256, 2) void ncc_main(const float* __restrict__ Iin,
                                                   const float* __restrict__ Jin,
                                                   float* __restrict__ out)
{
    const int tx0 = blockIdx.x * TX;
    const int ty0 = blockIdx.y * TY;
    const int b   = blockIdx.z >> 3;
    const int tz0 = (blockIdx.z & 7) * 16;
    const int tid = threadIdx.x;
    const int lx  = tid & 15;       // Phase-B x
    const int ly  = tid >> 4;       // Phase-B y (0..15)

    const float* __restrict__ Ib = Iin + b * (DSZ * DSZ * DSZ);
    const float* __restrict__ Jb = Jin + b * (DSZ * DSZ * DSZ);

    // s4m: (sumI,sumJ,sumII,sumJJ), row stride 17 f4 = 68 words (≡4 mod 32:
    //   b128 reads/writes land class-uniform -> conflict-free).
    // s1v: sumIJ scalar rows, stride 24 words (24·ly mod 32 = {0,24,16,8} ->
    //   exactly 2 lanes/bank on reads = free).
    __shared__ float4 s4m[4][PY][17];
    __shared__ float  s1v[4][PY][24];

    // ---- Phase-A static mapping (tid < 192: waves 0-2) ----
    const bool isA = (tid < 192);
    const int  pA  = (tid >= 96) ? 1 : 0;      // which of the 2 planes this round
    const int  t2  = isA ? (tid - pA * 96) : 0;
    const int  rA  = t2 >> 2;                  // 0..23 halo row
    const int  xgA = t2 & 3;                   // group of 4 x-outputs
    const int  gyA = ty0 + rA - 4;
    const int  gxbA = tx0 + 4 * xgA - 4;
    const bool yokA = ((unsigned)gyA < (unsigned)DSZ);

    auto loadA = [&](const int rnd, float4* LI, float4* LJ) {
        const int zp = tz0 + 2 * rnd + pA - 4;
        const bool ok = yokA && ((unsigned)zp < (unsigned)DSZ);
        const int zoff = (zp * DSZ + gyA) * DSZ;
#pragma unroll
        for (int g = 0; g < 3; ++g) {
            const int gx = gxbA + 4 * g;
            LI[g] = make_float4(0.f, 0.f, 0.f, 0.f);
            LJ[g] = LI[g];
            if (ok && (unsigned)gx < (unsigned)DSZ) {
                LI[g] = *(const float4*)(Ib + zoff + gx);
                LJ[g] = *(const float4*)(Jb + zoff + gx);
            }
        }
    };

    auto computeA = [&](const int rnd, const float4* LI, const float4* LJ) {
        float vi[12], vj[12];
#pragma unroll
        for (int g = 0; g < 3; ++g) {
            vi[4*g+0]=LI[g].x; vi[4*g+1]=LI[g].y; vi[4*g+2]=LI[g].z; vi[4*g+3]=LI[g].w;
            vj[4*g+0]=LJ[g].x; vj[4*g+1]=LJ[g].y; vj[4*g+2]=LJ[g].z; vj[4*g+3]=LJ[g].w;
        }
        float wI=0.f, wJ=0.f, wII=0.f, wJJ=0.f, wIJ=0.f;
#pragma unroll
        for (int k = 0; k < 9; ++k) {
            wI += vi[k]; wJ += vj[k];
            wII = fmaf(vi[k], vi[k], wII);
            wJJ = fmaf(vj[k], vj[k], wJJ);
            wIJ = fmaf(vi[k], vj[k], wIJ);
        }
        const int sl = (rnd & 1) * 2 + pA;
        float mIJ[4];
        s4m[sl][rA][4*xgA] = make_float4(wI, wJ, wII, wJJ);
        mIJ[0] = wIJ;
#pragma unroll
        for (int j = 1; j < 4; ++j) {
            const float ai = vi[8+j], aj = vj[8+j];
            const float di = vi[j-1], dj = vj[j-1];
            wI += ai - di; wJ += aj - dj;
            wII += fmaf(ai, ai, -di * di);
            wJJ += fmaf(aj, aj, -dj * dj);
            wIJ += fmaf(ai, aj, -di * dj);
            s4m[sl][rA][4*xgA + j] = make_float4(wI, wJ, wII, wJJ);
            mIJ[j] = wIJ;
        }
        *(float4*)&s1v[sl][rA][4*xgA] = make_float4(mIJ[0], mIJ[1], mIJ[2], mIJ[3]);
    };

    // ---- ring-of-8 z-window state (compile-time slots via full unroll) ----
    float4 ring4[8]; float ring1[8];
#pragma unroll
    for (int i = 0; i < 8; ++i) { ring4[i] = make_float4(0.f,0.f,0.f,0.f); ring1[i] = 0.f; }
    float4 z4 = make_float4(0.f, 0.f, 0.f, 0.f);
    float  z1 = 0.f;
    float  acc = 0.f;

    // ---- prologue: stage round 0 ----
    {
        float4 LI[3], LJ[3];
        if (isA) { loadA(0, LI, LJ); computeA(0, LI, LJ); }
    }
    __syncthreads();

#pragma unroll
    for (int rnd = 0; rnd < 12; ++rnd) {
        // T14: issue next round's global loads BEFORE Phase B consumes LDS
        float4 NI[3], NJ[3];
        if (rnd < 11 && isA) loadA(rnd + 1, NI, NJ);

        // ---- Phase B: y-pass + ring z-update + epilogue, both planes ----
#pragma unroll
        for (int p = 0; p < 2; ++p) {
            const int sl = (rnd & 1) * 2 + p;
            float4 c4 = make_float4(0.f, 0.f, 0.f, 0.f);
            float  c1 = 0.f;
#pragma unroll
            for (int dy = 0; dy < 9; ++dy) {
                c4 = f4add(c4, s4m[sl][ly + dy][lx]);
                c1 += s1v[sl][ly + dy][lx];
            }
            const int zi = 2 * rnd + p;
            const int k  = zi & 7;
            z4 = f4add(z4, c4); z1 += c1;
            if (zi >= 8) {
                const float inv = 1.0f / 729.0f;
                const float uI = z4.x * inv;
                const float uJ = z4.y * inv;
                const float cross = z1 - uJ * z4.x - uI * z4.y + uI * uJ * 729.0f;
                const float Ivar  = z4.z - 2.0f * uI * z4.x + uI * uI * 729.0f;
                const float Jvar  = z4.w - 2.0f * uJ * z4.y + uJ * uJ * 729.0f;
                acc += cross * cross / (Ivar * Jvar + 1e-5f);
            }
            z4 = f4sub(z4, ring4[k]); z1 -= ring1[k];
            ring4[k] = c4; ring1[k] = c1;
        }

        // ---- Phase A for round rnd+1 (loads have had all of B to land) ----
        if (rnd < 11 && isA) computeA(rnd + 1, NI, NJ);
        __syncthreads();
    }

    // block reduction: wave shuffle then cross-wave via LDS
#pragma unroll
    for (int off = 32; off > 0; off >>= 1) acc += __shfl_down(acc, off);
    __shared__ float wpart[4];
    if ((tid & 63) == 0) wpart[tid >> 6] = acc;
    __syncthreads();
    if (tid == 0) {
        const float s = wpart[0] + wpart[1] + wpart[2] + wpart[3];
        atomicAdd(out, s * (-1.0f / NVOX));
    }
}

extern "C" void kernel_launch(void* const* d_in, const int* in_sizes, int n_in,
                              void* d_out, int out_size, void* d_ws, size_t ws_size,
                              hipStream_t stream)
{
    // setup_inputs order: d_in[0] = y_pred (J), d_in[1] = y_true (I)
    const float* J = (const float*)d_in[0];
    const float* I = (const float*)d_in[1];
    float* out = (float*)d_out;

    ncc_zero<<<dim3(1), dim3(1), 0, stream>>>(out);
    dim3 grid(DSZ / TX, DSZ / TY, 2 * (DSZ / 16));  // 8 x 8 x 16 = 1024 blocks
    ncc_main<<<grid, dim3(256), 0, stream>>>(I, J, out);
}

// Round 6
// 59.010 us; speedup vs baseline: 7.6424x; 7.6424x over previous
//
#include <hip/hip_runtime.h>

#define DSZ 128
#define TX 16
#define TY 16
#define PY 24            // TY + 8 halo
#define NVOX 4194304.0f

__global__ void ncc_zero(float* out) { out[0] = 0.0f; }

__device__ __forceinline__ float4 f4add(const float4 a, const float4 b) {
    return make_float4(a.x + b.x, a.y + b.y, a.z + b.z, a.w + b.w);
}
__device__ __forceinline__ float4 f4sub(const float4 a, const float4 b) {
    return make_float4(a.x - b.x, a.y - b.y, a.z - b.z, a.w - b.w);
}

__global__ __launch_bounds__(256, 2) void ncc_main(const float* __restrict__ Iin,
                                                   const float* __restrict__ Jin,
                                                   float* __restrict__ out)
{
    const int tx0 = blockIdx.x * TX;
    const int ty0 = blockIdx.y * TY;
    const int b   = blockIdx.z >> 3;
    const int tz0 = (blockIdx.z & 7) * 16;
    const int tid = threadIdx.x;
    const int lx  = tid & 15;       // Phase-B x
    const int ly  = tid >> 4;       // Phase-B y (0..15)

    const float* __restrict__ Ib = Iin + b * (DSZ * DSZ * DSZ);
    const float* __restrict__ Jb = Jin + b * (DSZ * DSZ * DSZ);

    // s4m row stride 17 f4 = 68 words (≡4 mod 32).
    // s1v scalar rows, stride 24: read bank = lx + 24*ly' mod 32 ->
    //   exactly 2 lanes/bank for every dy (free, m136).
    __shared__ float4 s4m[4][PY][17];
    __shared__ float  s1v[4][PY][24];

    // ---- Phase-A static mapping (tid < 192: waves 0-2) ----
    const bool isA = (tid < 192);
    const int  pA  = (tid >= 96) ? 1 : 0;
    const int  t2  = isA ? (tid - pA * 96) : 0;
    const int  rA  = t2 >> 2;                  // 0..23 halo row
    const int  xgA = t2 & 3;                   // group of 4 x-outputs
    const int  gyA = ty0 + rA - 4;
    const int  gxbA = tx0 + 4 * xgA - 4;
    const bool yokA = ((unsigned)gyA < (unsigned)DSZ);

    auto loadA = [&](const int rnd, float4* LI, float4* LJ) {
        const int zp = tz0 + 2 * rnd + pA - 4;
        const bool ok = yokA && ((unsigned)zp < (unsigned)DSZ);
        const int zoff = (zp * DSZ + gyA) * DSZ;
#pragma unroll
        for (int g = 0; g < 3; ++g) {
            const int gx = gxbA + 4 * g;
            LI[g] = make_float4(0.f, 0.f, 0.f, 0.f);
            LJ[g] = LI[g];
            if (ok && (unsigned)gx < (unsigned)DSZ) {
                LI[g] = *(const float4*)(Ib + zoff + gx);
                LJ[g] = *(const float4*)(Jb + zoff + gx);
            }
        }
    };

    auto computeA = [&](const int rnd, const float4* LI, const float4* LJ) {
        float vi[12], vj[12];
#pragma unroll
        for (int g = 0; g < 3; ++g) {
            vi[4*g+0]=LI[g].x; vi[4*g+1]=LI[g].y; vi[4*g+2]=LI[g].z; vi[4*g+3]=LI[g].w;
            vj[4*g+0]=LJ[g].x; vj[4*g+1]=LJ[g].y; vj[4*g+2]=LJ[g].z; vj[4*g+3]=LJ[g].w;
        }
        float wI=0.f, wJ=0.f, wII=0.f, wJJ=0.f, wIJ=0.f;
#pragma unroll
        for (int k = 0; k < 9; ++k) {
            wI += vi[k]; wJ += vj[k];
            wII = fmaf(vi[k], vi[k], wII);
            wJJ = fmaf(vj[k], vj[k], wJJ);
            wIJ = fmaf(vi[k], vj[k], wIJ);
        }
        const int sl = (rnd & 1) * 2 + pA;
        float mIJ[4];
        s4m[sl][rA][4*xgA] = make_float4(wI, wJ, wII, wJJ);
        mIJ[0] = wIJ;
#pragma unroll
        for (int j = 1; j < 4; ++j) {
            const float ai = vi[8+j], aj = vj[8+j];
            const float di = vi[j-1], dj = vj[j-1];
            wI += ai - di; wJ += aj - dj;
            wII += fmaf(ai, ai, -di * di);
            wJJ += fmaf(aj, aj, -dj * dj);
            wIJ += fmaf(ai, aj, -di * dj);
            s4m[sl][rA][4*xgA + j] = make_float4(wI, wJ, wII, wJJ);
            mIJ[j] = wIJ;
        }
        *(float4*)&s1v[sl][rA][4*xgA] = make_float4(mIJ[0], mIJ[1], mIJ[2], mIJ[3]);
    };

    // ---- 9-plane rolling z-window: shift registers (compile-time indices,
    //      works with NON-unrolled round loop) ----
    float rb0[9], rb1[9], rb2[9], rb3[9], rb4[9];
#pragma unroll
    for (int i = 0; i < 9; ++i) { rb0[i]=0.f; rb1[i]=0.f; rb2[i]=0.f; rb3[i]=0.f; rb4[i]=0.f; }
    float zs0=0.f, zs1=0.f, zs2=0.f, zs3=0.f, zs4=0.f;
    float acc = 0.f;

    // ---- prologue: stage round 0 ----
    {
        float4 LI[3], LJ[3];
        if (isA) { loadA(0, LI, LJ); computeA(0, LI, LJ); }
    }
    __syncthreads();

#pragma unroll 1                    // keep the loop rolled: spill protection
    for (int rnd = 0; rnd < 12; ++rnd) {
        // T14: issue next round's global loads BEFORE Phase B consumes LDS
        float4 NI[3], NJ[3];
        const bool pre = (rnd < 11) && isA;
        if (pre) loadA(rnd + 1, NI, NJ);

        // ---- Phase B: y-pass + rolling z-update + epilogue, both planes ----
#pragma unroll
        for (int p = 0; p < 2; ++p) {
            const int sl = (rnd & 1) * 2 + p;
            float4 c4 = make_float4(0.f, 0.f, 0.f, 0.f);
            float  c1 = 0.f;
#pragma unroll
            for (int dy = 0; dy < 9; ++dy) {
                c4 = f4add(c4, s4m[sl][ly + dy][lx]);
                c1 += s1v[sl][ly + dy][lx];
            }

            zs0 += c4.x - rb0[0]; zs1 += c4.y - rb1[0]; zs2 += c4.z - rb2[0];
            zs3 += c4.w - rb3[0]; zs4 += c1 - rb4[0];
#pragma unroll
            for (int i = 0; i < 8; ++i) {
                rb0[i]=rb0[i+1]; rb1[i]=rb1[i+1]; rb2[i]=rb2[i+1];
                rb3[i]=rb3[i+1]; rb4[i]=rb4[i+1];
            }
            rb0[8]=c4.x; rb1[8]=c4.y; rb2[8]=c4.z; rb3[8]=c4.w; rb4[8]=c1;

            if (2 * rnd + p >= 8) {
                const float inv = 1.0f / 729.0f;
                const float uI = zs0 * inv;
                const float uJ = zs1 * inv;
                const float cross = zs4 - uJ * zs0 - uI * zs1 + uI * uJ * 729.0f;
                const float Ivar  = zs2 - 2.0f * uI * zs0 + uI * uI * 729.0f;
                const float Jvar  = zs3 - 2.0f * uJ * zs1 + uJ * uJ * 729.0f;
                acc += cross * cross / (Ivar * Jvar + 1e-5f);
            }
        }

        // ---- Phase A for round rnd+1 (loads had all of Phase B to land) ----
        if (pre) computeA(rnd + 1, NI, NJ);
        __syncthreads();
    }

    // block reduction: wave shuffle then cross-wave via LDS
#pragma unroll
    for (int off = 32; off > 0; off >>= 1) acc += __shfl_down(acc, off);
    __shared__ float wpart[4];
    if ((tid & 63) == 0) wpart[tid >> 6] = acc;
    __syncthreads();
    if (tid == 0) {
        const float s = wpart[0] + wpart[1] + wpart[2] + wpart[3];
        atomicAdd(out, s * (-1.0f / NVOX));
    }
}

extern "C" void kernel_launch(void* const* d_in, const int* in_sizes, int n_in,
                              void* d_out, int out_size, void* d_ws, size_t ws_size,
                              hipStream_t stream)
{
    // setup_inputs order: d_in[0] = y_pred (J), d_in[1] = y_true (I)
    const float* J = (const float*)d_in[0];
    const float* I = (const float*)d_in[1];
    float* out = (float*)d_out;

    ncc_zero<<<dim3(1), dim3(1), 0, stream>>>(out);
    dim3 grid(DSZ / TX, DSZ / TY, 2 * (DSZ / 16));  // 8 x 8 x 16 = 1024 blocks
    ncc_main<<<grid, dim3(256), 0, stream>>>(I, J, out);
}